// Round 8
// baseline (171.375 us; speedup 1.0000x reference)
//
#include <hip/hip_runtime.h>
#include <math.h>

// DIN fused, round 8: max-occupancy din_main (512 thr, 8 waves, 4 blocks/CU =
// 32 waves/CU) + swapped-operand MFMA (C[h][s]) so the h-reduce is 2 permlane
// swaps instead of a 16-step DPP chain; bias via MFMA acc-init.
//  k0 prep: A'/D' in fragment-major coalesced layout, Bm [d][h] bf16,
//           fw1T pre-swizzled bf16.
//  k2 FC head: MFMA, 16 b/block (unchanged).

#define S_LEN 200
#define S_PAD 208

typedef __attribute__((ext_vector_type(8))) short short8;
typedef __attribute__((ext_vector_type(4))) float f32x4;

__device__ __forceinline__ unsigned short f2b(float f) {
  union { float f; unsigned u; } x; x.f = f;
  unsigned r = x.u + 0x7fffu + ((x.u >> 16) & 1u);
  return (unsigned short)(r >> 16);
}
__device__ __forceinline__ float b2f(unsigned short h) {
  union { unsigned u; float f; } x; x.u = ((unsigned)h) << 16; return x.f;
}
__device__ __forceinline__ unsigned cvt_pk_bf16(float lo, float hi) {
  unsigned r;
  asm("v_cvt_pk_bf16_f32 %0, %1, %2" : "=v"(r) : "v"(lo), "v"(hi));
  return r;
}

// [row][64] bf16 tile, row stride 128 B (XOR row&7 into byte b4..6)
__device__ __forceinline__ int swzB(int row, int col) {
  int byte = row * 128 + col * 2;
  byte ^= (row & 7) << 4;
  return byte >> 1;
}
// [row][256] bf16 tile, row stride 512 B
__device__ __forceinline__ int swzW(int row, int col) {
  int byte = row * 512 + col * 2;
  byte ^= (row & 7) << 4;
  return byte >> 1;
}

__device__ __forceinline__ void async_g2l_16(const void* g, void* l) {
  __builtin_amdgcn_global_load_lds(
      (const __attribute__((address_space(1))) void*)g,
      (__attribute__((address_space(3))) void*)l, 16, 0, 0);
}

// DPP 16-lane reduce (xor1, xor2, ror4, ror8)
template <int CTRL>
__device__ __forceinline__ float dpp_add(float v) {
  const int t = __builtin_amdgcn_mov_dpp(__float_as_int(v), CTRL, 0xF, 0xF, true);
  return v + __int_as_float(t);
}
__device__ __forceinline__ float rowReduce16(float v) {
  v = dpp_add<0xB1>(v);
  v = dpp_add<0x4E>(v);
  v = dpp_add<0x124>(v);
  v = dpp_add<0x128>(v);
  return v;
}
// lane l <-> l^16 pairwise sum via v_permlane16_swap_b32 (VALU, gfx950)
__device__ __forceinline__ float permAdd16(float p) {
  float a = p, b = p;
  asm("v_permlane16_swap_b32 %0, %1" : "+v"(a), "+v"(b));
  return a + b;
}
// lane l <-> l^32 pairwise sum via v_permlane32_swap_b32
__device__ __forceinline__ float permAdd32(float p) {
  float a = p, b = p;
  asm("v_permlane32_swap_b32 %0, %1" : "+v"(a), "+v"(b));
  return a + b;
}
__device__ __forceinline__ float waveSum64(float v) {
  return permAdd32(permAdd16(rowReduce16(v)));
}

// ---------------- workspace layout (bytes) ----------------
#define WS_COMB 0          // bf16-swz [256 tiles][16][256]  (2 MB)
#define WS_AT   2097152    // A' frag-major bf16, 16 KB
#define WS_DT   2113536    // D' frag-major bf16, 16 KB
#define WS_BM   2129920    // Bm = W1b-W1c, [d][h] bf16, 16 KB
#define WS_FW1T 2146304    // fw1^T pre-swizzled bf16, 64 KB

// ================= k0: prep =================
__global__ __launch_bounds__(256)
void din_prep(const float* __restrict__ aw1, const float* __restrict__ fw1,
              char* __restrict__ ws)
{
  unsigned short* ATc  = (unsigned short*)(ws + WS_AT);
  unsigned short* DTc  = (unsigned short*)(ws + WS_DT);
  unsigned short* Bm   = (unsigned short*)(ws + WS_BM);
  unsigned short* FW1T = (unsigned short*)(ws + WS_FW1T);
  const int blk = blockIdx.x, tid = threadIdx.x;

  if (blk < 32) {               // A', D' in fragment-major coalesced layout
    const int i = blk * 256 + tid;        // 0..8191
    const int h = i >> 6, d = i & 63;
    const float a  = aw1[d * 128 + h];
    const float c  = aw1[(128 + d) * 128 + h];
    const float dd = aw1[(192 + d) * 128 + h];
    // frag index: lane = rq*16+hl reads 16B at ((hg*2+ht)*2+kk)*512 + lane*8
    const int hg = h >> 5, ht = (h >> 4) & 1, hl = h & 15;
    const int kk = d >> 5, rq = (d >> 3) & 3, j = d & 7;
    const int o = (hg * 2 + ht) * 1024 + kk * 512 + rq * 128 + hl * 8 + j;
    ATc[o] = f2b(a + c);
    DTc[o] = f2b(dd);
  } else if (blk < 64) {        // Bm : [d][h]
    const int jj = (blk - 32) * 256 + tid;
    const int d = jj >> 7, h = jj & 127;
    Bm[jj] = f2b(aw1[(64 + d) * 128 + h] - aw1[(128 + d) * 128 + h]);
  } else {                      // fw1T swizzled image
    const int i = (blk - 64) * 256 + tid;
    const int o = 2 * i;
    const int h = o >> 9;
    const int rr = o & 511;
    const int d = (rr ^ ((h & 7) << 4)) >> 1;
    FW1T[i] = f2b(fw1[d * 128 + h]);
  }
}

// ================= k1: main =================
__global__ __launch_bounds__(512, 8)
void din_main(const int* __restrict__ uf, const int* __restrict__ tif,
              const int* __restrict__ bseq,
              const float* __restrict__ e0, const float* __restrict__ e1,
              const float* __restrict__ ei,
              const float* __restrict__ ab1, const float* __restrict__ aw2,
              char* __restrict__ ws)
{
  __shared__ unsigned short sBeh[13312];  // 26624 B; [0,16KB) aliased as Bm stage
  __shared__ int   sIdx[800];             // 3200
  __shared__ float sT[256];               // 1024 (4 b x 64)
  __shared__ float sCH[512];              // 2048 (4 b x 128, ab1 folded)
  __shared__ float sPart[4][S_PAD];       // 3328 (per h-group)
  __shared__ float sScores[S_PAD];        // 832
  __shared__ float sPool[8][64];          // 2048
  __shared__ float sRedS[4];

  unsigned short* combS = (unsigned short*)(ws + WS_COMB);
  const unsigned short* ATc = (const unsigned short*)(ws + WS_AT);
  const unsigned short* DTc = (const unsigned short*)(ws + WS_DT);

  const int tid  = threadIdx.x;
  const int lane = tid & 63;
  const int wv   = tid >> 6;       // 0..7
  const int hl   = lane & 15;
  const int rq   = lane >> 4;      // 0..3
  const int hg   = wv & 3;         // h-group (32 cols)
  const int sh   = wv >> 2;        // s-half
  const int bb   = blockIdx.x * 4;

  // ---- prologue ----
  for (int k = tid; k < 800; k += 512) sIdx[k] = bseq[bb * 200 + k];
  if (tid < 256) {
    const int g = tid >> 6, d = tid & 63, b = bb + g;
    const int u0 = uf[2 * b], u1 = uf[2 * b + 1], ti = tif[b];
    const float tv = ei[(size_t)ti * 64 + d];
    sT[g * 64 + d] = tv;
    unsigned short* ct = combS + (size_t)(b >> 4) * 4096;
    const int row = b & 15;
    ct[swzW(row, 192 + d)] = f2b(tv);
    ct[swzW(row, d)]       = f2b(e0[(size_t)u0 * 64 + d]);
    ct[swzW(row, 64 + d)]  = f2b(e1[(size_t)u1 * 64 + d]);
  }
  if (tid < 128) {   // zero pad rows 200..207 (disjoint from Bm low 16KB)
    const int row = 200 + (tid >> 4), c = (tid & 15) * 4;
    ushort4 z = {0, 0, 0, 0};
    *(ushort4*)&sBeh[swzB(row, c)] = z;
  }
  {  // stage Bm (16 KB) into sBeh low region
    char* dst = (char*)sBeh;
    const char* src = ws + WS_BM;
    async_g2l_16(src + tid * 16, dst + tid * 16);
    async_g2l_16(src + 8192 + tid * 16, dst + 8192 + tid * 16);
  }
  // per-lane w2 values for the swapped C[h][s] layout: h = hg*32+ht*16+rq*4+r
  float4 w2v0 = *(const float4*)(aw2 + hg * 32 + rq * 4);
  float4 w2v1 = *(const float4*)(aw2 + hg * 32 + 16 + rq * 4);
  __syncthreads();  // A: Bm staged (vmcnt drained), sIdx/sT/pad ready

  // ---- batched g=0 gathers (latency hidden under cH) ----
  float4 gv[7];
#pragma unroll
  for (int it = 0; it < 7; ++it) {
    const int row = it * 32 + (tid >> 4);
    if (row < S_LEN) {
      const int idx = sIdx[row];
      gv[it] = *(const float4*)(ei + (size_t)idx * 64 + (tid & 15) * 4);
    }
  }
  __builtin_amdgcn_sched_barrier(0);

  // ---- cH[b][h2] = t[b].Bm[:,h2] + ab1[h2] ----
  {
    const unsigned short* sBm = sBeh;
    const int b4 = tid >> 7, h2 = tid & 127;
    float c = ab1[h2];
    const float* t = sT + b4 * 64;
#pragma unroll 8
    for (int d = 0; d < 64; ++d)
      c = fmaf(t[d], b2f(sBm[d * 128 + h2]), c);
    sCH[b4 * 128 + h2] = c;
  }
  __syncthreads();  // B: cH ready; Bm region free; g0 gathers drained

  // ---- per-b loop ----
  for (int g = 0; g < 4; ++g) {
    const int b = bb + g;

    // commit gv -> sBeh (bf16, swizzled)
#pragma unroll
    for (int it = 0; it < 7; ++it) {
      const int row = it * 32 + (tid >> 4);
      if (row < S_LEN) {
        const float4 v = gv[it];
        uint2 pk;
        pk.x = cvt_pk_bf16(v.x, v.y);
        pk.y = cvt_pk_bf16(v.z, v.w);
        *(uint2*)&sBeh[swzB(row, (tid & 15) * 4)] = pk;
      }
    }

    // W_eff fragments: w[ht][kk] = A' + t(.)D'  (A'/D' streamed from L1/L2)
    short8 w[2][2];
    {
#pragma unroll
      for (int kk = 0; kk < 2; ++kk) {
        const float* tb = sT + g * 64 + kk * 32 + rq * 8;
        const float4 x = *(const float4*)tb;
        const float4 y = *(const float4*)(tb + 4);
        const float tt[8] = {x.x, x.y, x.z, x.w, y.x, y.y, y.z, y.w};
#pragma unroll
        for (int ht = 0; ht < 2; ++ht) {
          const int fo = (hg * 2 + ht) * 1024 + kk * 512 + lane * 8;
          const short8 a8 = *(const short8*)(ATc + fo);
          const short8 d8 = *(const short8*)(DTc + fo);
          union { short8 s; unsigned u[4]; } o;
#pragma unroll
          for (int p = 0; p < 4; ++p) {
            const float lo = fmaf(tt[2*p],   b2f((unsigned short)d8[2*p]),   b2f((unsigned short)a8[2*p]));
            const float hi = fmaf(tt[2*p+1], b2f((unsigned short)d8[2*p+1]), b2f((unsigned short)a8[2*p+1]));
            o.u[p] = cvt_pk_bf16(lo, hi);
          }
          w[ht][kk] = o.s;
        }
      }
    }
    __syncthreads();  // (1) beh ready

    // bias as acc-init: cH4[ht][r] = cH[b][hg*32+ht*16+rq*4+r]
    const f32x4 cH40 = *(const f32x4*)&sCH[g * 128 + hg * 32 + rq * 4];
    const f32x4 cH41 = *(const f32x4*)&sCH[g * 128 + hg * 32 + 16 + rq * 4];

    // MFMA phase (swapped operands): C[h][s], col=lane&15=s, row=h
    const int tbase = sh * 7;
    const int tcnt  = sh ? 6 : 7;
#pragma unroll 2
    for (int ti = 0; ti < tcnt; ++ti) {
      const int tile = tbase + ti;
      const short8 av0 = *(const short8*)&sBeh[swzB(tile * 16 + hl, rq * 8)];
      const short8 av1 = *(const short8*)&sBeh[swzB(tile * 16 + hl, 32 + rq * 8)];
      f32x4 acc = cH40;
      acc = __builtin_amdgcn_mfma_f32_16x16x32_bf16(w[0][0], av0, acc, 0, 0, 0);
      acc = __builtin_amdgcn_mfma_f32_16x16x32_bf16(w[0][1], av1, acc, 0, 0, 0);
      float p;
      p  = fmaxf(acc[0], 0.f) * w2v0.x;
      p  = fmaf(fmaxf(acc[1], 0.f), w2v0.y, p);
      p  = fmaf(fmaxf(acc[2], 0.f), w2v0.z, p);
      p  = fmaf(fmaxf(acc[3], 0.f), w2v0.w, p);
      f32x4 acc2 = cH41;
      acc2 = __builtin_amdgcn_mfma_f32_16x16x32_bf16(w[1][0], av0, acc2, 0, 0, 0);
      acc2 = __builtin_amdgcn_mfma_f32_16x16x32_bf16(w[1][1], av1, acc2, 0, 0, 0);
      p  = fmaf(fmaxf(acc2[0], 0.f), w2v1.x, p);
      p  = fmaf(fmaxf(acc2[1], 0.f), w2v1.y, p);
      p  = fmaf(fmaxf(acc2[2], 0.f), w2v1.z, p);
      p  = fmaf(fmaxf(acc2[3], 0.f), w2v1.w, p);
      // reduce over q-groups (lanes l, l^16, l^32, l^48) — pure VALU
      p = permAdd32(permAdd16(p));
      if (lane < 16) sPart[hg][tile * 16 + lane] = p;
    }
    __syncthreads();  // (2) partials ready

    // softmax (no max-shift; shift-invariant, |s| small for this data)
    float e = 0.f;
    if (tid < S_PAD) {
      if (tid < S_LEN)
        e = __expf((sPart[0][tid] + sPart[1][tid]) + (sPart[2][tid] + sPart[3][tid]));
      sScores[tid] = e;
    }
    if (wv < 4) {
      const float s = waveSum64(e);
      if (lane == 0) sRedS[wv] = s;
    }
    __syncthreads();  // (3) sScores + sums ready

    const float invS = 1.f / (sRedS[0] + sRedS[1] + sRedS[2] + sRedS[3]);

    // batched next-b gather issue (crosses only barrier (4))
    if (g < 3) {
#pragma unroll
      for (int it = 0; it < 7; ++it) {
        const int row = it * 32 + (tid >> 4);
        if (row < S_LEN) {
          const int idx = sIdx[(g + 1) * 200 + row];
          gv[it] = *(const float4*)(ei + (size_t)idx * 64 + (tid & 15) * 4);
        }
      }
    }
    __builtin_amdgcn_sched_barrier(0);

    // pooling: lane covers col pair (2e2,2e2+1), rows {16k + 2wv + rr}
    {
      const int e2 = lane & 31, rr = lane >> 5;
      float p0 = 0.f, p1 = 0.f;
#pragma unroll
      for (int k = 0; k < 13; ++k) {
        const int rowk = 16 * k + 2 * wv + rr;
        const float2 sc2 = *(const float2*)&sScores[16 * k + 2 * wv];
        const float sv = rr ? sc2.y : sc2.x;
        const unsigned u = *(const unsigned*)&sBeh[swzB(rowk, e2 * 2)];
        p0 = fmaf(sv, __int_as_float((int)(u << 16)), p0);
        p1 = fmaf(sv, __int_as_float((int)(u & 0xffff0000u)), p1);
      }
      p0 = permAdd32(p0);
      p1 = permAdd32(p1);
      if (lane < 32) {
        float2 pr; pr.x = p0; pr.y = p1;
        *(float2*)&sPool[wv][e2 * 2] = pr;
      }
    }
    __syncthreads();  // (4) sPool ready; sBeh free; next-b gathers drained

    if (tid < 64) {
      float a = 0.f;
#pragma unroll
      for (int w8 = 0; w8 < 8; ++w8) a += sPool[w8][tid];
      combS[(size_t)(b >> 4) * 4096 + swzW(b & 15, 128 + tid)] = f2b(a * invS);
    }
  }
}

// ================= k2: FC head =================
__global__ __launch_bounds__(256, 2)
void din_fc(const float* __restrict__ fb1, const float* __restrict__ fw2,
            const float* __restrict__ fb2, const char* __restrict__ ws,
            float* __restrict__ out)
{
  __shared__ unsigned short sW[32768];   // fw1T swizzled image, 64 KB
  __shared__ unsigned short sA[4096];    // comb tile (pre-swizzled bf16), 8 KB
  __shared__ float sO[64];

  const int tid  = threadIdx.x;
  const int lane = tid & 63;
  const int wv   = tid >> 6;
  const int bb   = blockIdx.x * 16;

  {
    const char* srcW = ws + WS_FW1T;
    char* dstW = (char*)sW;
#pragma unroll
    for (int it = 0; it < 16; ++it)
      async_g2l_16(srcW + it * 4096 + tid * 16, dstW + it * 4096 + tid * 16);
    const char* srcA = ws + WS_COMB + (size_t)blockIdx.x * 8192;
    char* dstA = (char*)sA;
    async_g2l_16(srcA + tid * 16, dstA + tid * 16);
    async_g2l_16(srcA + 4096 + tid * 16, dstA + 4096 + tid * 16);
  }
  __syncthreads();

  const int hl = lane & 15, rq = lane >> 4;
  const int h0 = wv * 32 + hl, h1 = h0 + 16;
  f32x4 acc0 = {0.f, 0.f, 0.f, 0.f};
  f32x4 acc1 = {0.f, 0.f, 0.f, 0.f};
#pragma unroll
  for (int kk = 0; kk < 8; ++kk) {
    const short8 av = *(const short8*)&sA[swzW(hl, kk * 32 + rq * 8)];
    const short8 b0 = *(const short8*)&sW[swzW(h0, kk * 32 + rq * 8)];
    const short8 b1 = *(const short8*)&sW[swzW(h1, kk * 32 + rq * 8)];
    acc0 = __builtin_amdgcn_mfma_f32_16x16x32_bf16(av, b0, acc0, 0, 0, 0);
    acc1 = __builtin_amdgcn_mfma_f32_16x16x32_bf16(av, b1, acc1, 0, 0, 0);
  }
  const float fb10 = fb1[h0], fb11 = fb1[h1];
  const float fw20 = fw2[h0], fw21 = fw2[h1];
#pragma unroll
  for (int r = 0; r < 4; ++r) {
    float v = fmaxf(acc0[r] + fb10, 0.f) * fw20
            + fmaxf(acc1[r] + fb11, 0.f) * fw21;
    v += __shfl_xor(v, 1, 64);
    v += __shfl_xor(v, 2, 64);
    v += __shfl_xor(v, 4, 64);
    v += __shfl_xor(v, 8, 64);
    if (hl == 0) sO[wv * 16 + rq * 4 + r] = v;
  }
  __syncthreads();
  if (tid < 16)
    out[bb + tid] = sO[tid] + sO[16 + tid] + sO[32 + tid] + sO[48 + tid] + fb2[0];
}

extern "C" void kernel_launch(void* const* d_in, const int* in_sizes, int n_in,
                              void* d_out, int out_size, void* d_ws, size_t ws_size,
                              hipStream_t stream) {
  const int*   uf   = (const int*)d_in[0];
  const int*   tif  = (const int*)d_in[1];
  const int*   bseq = (const int*)d_in[2];
  const float* e0   = (const float*)d_in[3];
  const float* e1   = (const float*)d_in[4];
  const float* ei   = (const float*)d_in[5];
  const float* aw1  = (const float*)d_in[6];
  const float* ab1  = (const float*)d_in[7];
  const float* aw2  = (const float*)d_in[8];
  // d_in[9] = ab2 (unused: softmax shift-invariant)
  const float* fw1  = (const float*)d_in[10];
  const float* fb1  = (const float*)d_in[11];
  const float* fw2  = (const float*)d_in[12];
  const float* fb2  = (const float*)d_in[13];
  float* o = (float*)d_out;
  char* ws = (char*)d_ws;

  din_prep<<<dim3(192), dim3(256), 0, stream>>>(aw1, fw1, ws);
  din_main<<<dim3(1024), dim3(512), 0, stream>>>(uf, tif, bseq, e0, e1, ei,
                                                 ab1, aw2, ws);
  din_fc<<<dim3(256), dim3(256), 0, stream>>>(fb1, fw2, fb2, ws, o);
}

// Round 9
// 63.482 us; speedup vs baseline: 2.6996x; 2.6996x over previous
//
#include <hip/hip_runtime.h>
#include <math.h>

// DIN fused, round 9: one-b-per-block din_main (4096 independent blocks) so
// gathers are in flight continuously; cH/t hoisted to prep2; swapped-operand
// MFMA epilogue (permlane) from R8 without its register cap.
//  k0  prep : A'/D' frag-major bf16, Bm [d][h] bf16, fw1T pre-swizzled bf16.
//  k0b prep2: cH[b][h] = t_b.Bm[:,h]+ab1[h]; tS[b][d]; comb u0/u1/t parts.
//  k1  main : gather -> swizzled bf16 LDS -> MFMA -> softmax -> pool -> comb.
//  k2  fc   : relu(comb@fw1+b1)@fw2+b2 via MFMA, 16 b/block.

#define S_LEN 200
#define S_PAD 208

typedef __attribute__((ext_vector_type(8))) short short8;
typedef __attribute__((ext_vector_type(4))) float f32x4;

__device__ __forceinline__ unsigned short f2b(float f) {
  union { float f; unsigned u; } x; x.f = f;
  unsigned r = x.u + 0x7fffu + ((x.u >> 16) & 1u);
  return (unsigned short)(r >> 16);
}
__device__ __forceinline__ float b2f(unsigned short h) {
  union { unsigned u; float f; } x; x.u = ((unsigned)h) << 16; return x.f;
}
__device__ __forceinline__ unsigned cvt_pk_bf16(float lo, float hi) {
  unsigned r;
  asm("v_cvt_pk_bf16_f32 %0, %1, %2" : "=v"(r) : "v"(lo), "v"(hi));
  return r;
}

// [row][64] bf16 tile, row stride 128 B (XOR row&7 into byte b4..6)
__device__ __forceinline__ int swzB(int row, int col) {
  int byte = row * 128 + col * 2;
  byte ^= (row & 7) << 4;
  return byte >> 1;
}
// [row][256] bf16 tile, row stride 512 B
__device__ __forceinline__ int swzW(int row, int col) {
  int byte = row * 512 + col * 2;
  byte ^= (row & 7) << 4;
  return byte >> 1;
}

__device__ __forceinline__ void async_g2l_16(const void* g, void* l) {
  __builtin_amdgcn_global_load_lds(
      (const __attribute__((address_space(1))) void*)g,
      (__attribute__((address_space(3))) void*)l, 16, 0, 0);
}

// DPP 16-lane reduce (xor1, xor2, ror4, ror8)
template <int CTRL>
__device__ __forceinline__ float dpp_add(float v) {
  const int t = __builtin_amdgcn_mov_dpp(__float_as_int(v), CTRL, 0xF, 0xF, true);
  return v + __int_as_float(t);
}
__device__ __forceinline__ float rowReduce16(float v) {
  v = dpp_add<0xB1>(v);
  v = dpp_add<0x4E>(v);
  v = dpp_add<0x124>(v);
  v = dpp_add<0x128>(v);
  return v;
}
__device__ __forceinline__ float permAdd16(float p) {
  float a = p, b = p;
  asm("v_permlane16_swap_b32 %0, %1" : "+v"(a), "+v"(b));
  return a + b;
}
__device__ __forceinline__ float permAdd32(float p) {
  float a = p, b = p;
  asm("v_permlane32_swap_b32 %0, %1" : "+v"(a), "+v"(b));
  return a + b;
}
__device__ __forceinline__ float waveSum64(float v) {
  return permAdd32(permAdd16(rowReduce16(v)));
}

// ---------------- workspace layout (bytes) ----------------
#define WS_COMB 0          // bf16-swz [256 tiles][16][256]  (2 MB)
#define WS_AT   2097152    // A' frag-major bf16, 16 KB
#define WS_DT   2113536    // D' frag-major bf16, 16 KB
#define WS_BM   2129920    // Bm = W1b-W1c, [d][h] bf16, 16 KB
#define WS_FW1T 2146304    // fw1^T pre-swizzled bf16, 64 KB
#define WS_CH   2211840    // cH f32 [4096][128] (2 MB)
#define WS_TS   4308992    // t rows f32 [4096][64] (1 MB)

// ================= k0: prep =================
__global__ __launch_bounds__(256)
void din_prep(const float* __restrict__ aw1, const float* __restrict__ fw1,
              char* __restrict__ ws)
{
  unsigned short* ATc  = (unsigned short*)(ws + WS_AT);
  unsigned short* DTc  = (unsigned short*)(ws + WS_DT);
  unsigned short* Bm   = (unsigned short*)(ws + WS_BM);
  unsigned short* FW1T = (unsigned short*)(ws + WS_FW1T);
  const int blk = blockIdx.x, tid = threadIdx.x;

  if (blk < 32) {               // A', D' in fragment-major coalesced layout
    const int i = blk * 256 + tid;        // 0..8191
    const int h = i >> 6, d = i & 63;
    const float a  = aw1[d * 128 + h];
    const float c  = aw1[(128 + d) * 128 + h];
    const float dd = aw1[(192 + d) * 128 + h];
    const int hg = h >> 5, ht = (h >> 4) & 1, hl = h & 15;
    const int kk = d >> 5, rq = (d >> 3) & 3, j = d & 7;
    const int o = (hg * 2 + ht) * 1024 + kk * 512 + rq * 128 + hl * 8 + j;
    ATc[o] = f2b(a + c);
    DTc[o] = f2b(dd);
  } else if (blk < 64) {        // Bm : [d][h]
    const int jj = (blk - 32) * 256 + tid;
    const int d = jj >> 7, h = jj & 127;
    Bm[jj] = f2b(aw1[(64 + d) * 128 + h] - aw1[(128 + d) * 128 + h]);
  } else {                      // fw1T swizzled image
    const int i = (blk - 64) * 256 + tid;
    const int o = 2 * i;
    const int h = o >> 9;
    const int rr = o & 511;
    const int d = (rr ^ ((h & 7) << 4)) >> 1;
    FW1T[i] = f2b(fw1[d * 128 + h]);
  }
}

// ================= k0b: prep2 (cH, tS, comb user/target parts) =============
__global__ __launch_bounds__(128)
void din_prep2(const int* __restrict__ uf, const int* __restrict__ tif,
               const float* __restrict__ e0, const float* __restrict__ e1,
               const float* __restrict__ ei, const float* __restrict__ ab1,
               char* __restrict__ ws)
{
  __shared__ float sTt[64];
  const unsigned short* Bm = (const unsigned short*)(ws + WS_BM);
  unsigned short* combS = (unsigned short*)(ws + WS_COMB);
  float* CHW = (float*)(ws + WS_CH);
  float* TS  = (float*)(ws + WS_TS);

  const int b = blockIdx.x, tid = threadIdx.x;
  const int ti = tif[b];

  if (tid < 64) {
    const float tv = ei[(size_t)ti * 64 + tid];
    sTt[tid] = tv;
    TS[(size_t)b * 64 + tid] = tv;
    const int u0 = uf[2 * b], u1 = uf[2 * b + 1];
    unsigned short* ct = combS + (size_t)(b >> 4) * 4096;
    const int row = b & 15;
    ct[swzW(row, 192 + tid)] = f2b(tv);
    ct[swzW(row, tid)]       = f2b(e0[(size_t)u0 * 64 + tid]);
    ct[swzW(row, 64 + tid)]  = f2b(e1[(size_t)u1 * 64 + tid]);
  }
  __syncthreads();

  // cH[b][h] = t . Bm[:,h] + ab1[h]
  const int h = tid;  // 0..127
  float c = ab1[h];
#pragma unroll 8
  for (int d = 0; d < 64; ++d)
    c = fmaf(sTt[d], b2f(Bm[d * 128 + h]), c);
  CHW[(size_t)b * 128 + h] = c;
}

// ================= k1: main (one b per block) =================
__global__ __launch_bounds__(256, 4)
void din_main(const int* __restrict__ bseq, const float* __restrict__ ei,
              const float* __restrict__ aw2, char* __restrict__ ws)
{
  __shared__ unsigned short sBeh[13312];  // 26624 B, swizzled bf16 [208][64]
  __shared__ float sPart[4][S_PAD];       // 3328
  __shared__ float sScores[S_PAD];        // 832
  __shared__ float sPool[4][64];          // 1024
  __shared__ float sRedS[4];

  unsigned short* combS = (unsigned short*)(ws + WS_COMB);
  const unsigned short* ATc = (const unsigned short*)(ws + WS_AT);
  const unsigned short* DTc = (const unsigned short*)(ws + WS_DT);
  const float* CHW = (const float*)(ws + WS_CH);
  const float* TS  = (const float*)(ws + WS_TS);

  const int b    = blockIdx.x;
  const int tid  = threadIdx.x;
  const int lane = tid & 63;
  const int wv   = tid >> 6;       // 0..3 = h-group (32 cols each)
  const int hl   = lane & 15;
  const int rq   = lane >> 4;      // 0..3

  // ---- 1. issue all 13 gathers immediately (idx read -> dependent load) ----
  float4 gv[13];
#pragma unroll
  for (int it = 0; it < 13; ++it) {
    const int row = it * 16 + (tid >> 4);
    if (row < S_LEN) {
      const int idx = bseq[b * S_LEN + row];
      gv[it] = *(const float4*)(ei + (size_t)idx * 64 + (tid & 15) * 4);
    }
  }
  __builtin_amdgcn_sched_barrier(0);

  // ---- 2. pad rows 200..207 ----
  if (tid < 128) {
    const int row = 200 + (tid >> 4), c = (tid & 15) * 4;
    ushort4 z = {0, 0, 0, 0};
    *(ushort4*)&sBeh[swzB(row, c)] = z;
  }

  // ---- 3. per-lane constants (all L2-hot ws reads) ----
  const float4 w2v0 = *(const float4*)(aw2 + wv * 32 + rq * 4);
  const float4 w2v1 = *(const float4*)(aw2 + wv * 32 + 16 + rq * 4);
  const f32x4 cH40 = *(const f32x4*)(CHW + (size_t)b * 128 + wv * 32 + rq * 4);
  const f32x4 cH41 = *(const f32x4*)(CHW + (size_t)b * 128 + wv * 32 + 16 + rq * 4);

  // ---- 4. W_eff fragments: w[ht][kk] = A' + t(.)D' ----
  short8 w[2][2];
#pragma unroll
  for (int kk = 0; kk < 2; ++kk) {
    const float* tb = TS + (size_t)b * 64 + kk * 32 + rq * 8;
    const float4 x = *(const float4*)tb;
    const float4 y = *(const float4*)(tb + 4);
    const float tt[8] = {x.x, x.y, x.z, x.w, y.x, y.y, y.z, y.w};
#pragma unroll
    for (int ht = 0; ht < 2; ++ht) {
      const int fo = (wv * 2 + ht) * 1024 + kk * 512 + lane * 8;
      const short8 a8 = *(const short8*)(ATc + fo);
      const short8 d8 = *(const short8*)(DTc + fo);
      union { short8 s; unsigned u[4]; } o;
#pragma unroll
      for (int p = 0; p < 4; ++p) {
        const float lo = fmaf(tt[2*p],   b2f((unsigned short)d8[2*p]),   b2f((unsigned short)a8[2*p]));
        const float hi = fmaf(tt[2*p+1], b2f((unsigned short)d8[2*p+1]), b2f((unsigned short)a8[2*p+1]));
        o.u[p] = cvt_pk_bf16(lo, hi);
      }
      w[ht][kk] = o.s;
    }
  }

  // ---- 5. commit gathers -> swizzled bf16 LDS ----
#pragma unroll
  for (int it = 0; it < 13; ++it) {
    const int row = it * 16 + (tid >> 4);
    if (row < S_LEN) {
      const float4 v = gv[it];
      uint2 pk;
      pk.x = cvt_pk_bf16(v.x, v.y);
      pk.y = cvt_pk_bf16(v.z, v.w);
      *(uint2*)&sBeh[swzB(row, (tid & 15) * 4)] = pk;
    }
  }
  __syncthreads();  // (1) beh ready

  // ---- 6. MFMA (swapped operands): C[h][s], wave owns 32 h-cols ----
#pragma unroll 2
  for (int tile = 0; tile < 13; ++tile) {
    const short8 av0 = *(const short8*)&sBeh[swzB(tile * 16 + hl, rq * 8)];
    const short8 av1 = *(const short8*)&sBeh[swzB(tile * 16 + hl, 32 + rq * 8)];
    f32x4 acc = cH40;
    acc = __builtin_amdgcn_mfma_f32_16x16x32_bf16(w[0][0], av0, acc, 0, 0, 0);
    acc = __builtin_amdgcn_mfma_f32_16x16x32_bf16(w[0][1], av1, acc, 0, 0, 0);
    float p;
    p = fmaxf(acc[0], 0.f) * w2v0.x;
    p = fmaf(fmaxf(acc[1], 0.f), w2v0.y, p);
    p = fmaf(fmaxf(acc[2], 0.f), w2v0.z, p);
    p = fmaf(fmaxf(acc[3], 0.f), w2v0.w, p);
    f32x4 acc2 = cH41;
    acc2 = __builtin_amdgcn_mfma_f32_16x16x32_bf16(w[1][0], av0, acc2, 0, 0, 0);
    acc2 = __builtin_amdgcn_mfma_f32_16x16x32_bf16(w[1][1], av1, acc2, 0, 0, 0);
    p = fmaf(fmaxf(acc2[0], 0.f), w2v1.x, p);
    p = fmaf(fmaxf(acc2[1], 0.f), w2v1.y, p);
    p = fmaf(fmaxf(acc2[2], 0.f), w2v1.z, p);
    p = fmaf(fmaxf(acc2[3], 0.f), w2v1.w, p);
    p = permAdd32(permAdd16(p));   // reduce over q-groups (pure VALU)
    if (lane < 16) sPart[wv][tile * 16 + lane] = p;
  }
  __syncthreads();  // (2) partials ready

  // ---- 7. softmax (no max-shift; shift-invariant, |s| small) ----
  float e = 0.f;
  if (tid < S_PAD) {
    if (tid < S_LEN)
      e = __expf((sPart[0][tid] + sPart[1][tid]) + (sPart[2][tid] + sPart[3][tid]));
    sScores[tid] = e;
  }
  {
    const float s = waveSum64(e);
    if (lane == 0) sRedS[wv] = s;
  }
  __syncthreads();  // (3) sScores + sums ready

  const float invS = 1.f / (sRedS[0] + sRedS[1] + sRedS[2] + sRedS[3]);

  // ---- 8. pooling: lane = col pair (2e2,2e2+1); wave covers rows 4wv..+3 mod 16
  {
    const int e2 = lane & 31, rr = lane >> 5;
    float p0 = 0.f, p1 = 0.f;
#pragma unroll
    for (int k = 0; k < 13; ++k) {
      const int base = 16 * k + 4 * wv + 2 * rr;
      const float2 sc2 = *(const float2*)&sScores[base];
      const unsigned u0 = *(const unsigned*)&sBeh[swzB(base, e2 * 2)];
      p0 = fmaf(sc2.x, __int_as_float((int)(u0 << 16)), p0);
      p1 = fmaf(sc2.x, __int_as_float((int)(u0 & 0xffff0000u)), p1);
      const unsigned u1 = *(const unsigned*)&sBeh[swzB(base + 1, e2 * 2)];
      p0 = fmaf(sc2.y, __int_as_float((int)(u1 << 16)), p0);
      p1 = fmaf(sc2.y, __int_as_float((int)(u1 & 0xffff0000u)), p1);
    }
    p0 = permAdd32(p0);
    p1 = permAdd32(p1);
    if (lane < 32) {
      float2 pr; pr.x = p0; pr.y = p1;
      *(float2*)&sPool[wv][e2 * 2] = pr;
    }
  }
  __syncthreads();  // (4) sPool ready

  if (tid < 64) {
    const float a = sPool[0][tid] + sPool[1][tid] + sPool[2][tid] + sPool[3][tid];
    combS[(size_t)(b >> 4) * 4096 + swzW(b & 15, 128 + tid)] = f2b(a * invS);
  }
}

// ================= k2: FC head =================
__global__ __launch_bounds__(256, 2)
void din_fc(const float* __restrict__ fb1, const float* __restrict__ fw2,
            const float* __restrict__ fb2, const char* __restrict__ ws,
            float* __restrict__ out)
{
  __shared__ unsigned short sW[32768];   // fw1T swizzled image, 64 KB
  __shared__ unsigned short sA[4096];    // comb tile (pre-swizzled bf16), 8 KB
  __shared__ float sO[64];

  const int tid  = threadIdx.x;
  const int lane = tid & 63;
  const int wv   = tid >> 6;
  const int bb   = blockIdx.x * 16;

  {
    const char* srcW = ws + WS_FW1T;
    char* dstW = (char*)sW;
#pragma unroll
    for (int it = 0; it < 16; ++it)
      async_g2l_16(srcW + it * 4096 + tid * 16, dstW + it * 4096 + tid * 16);
    const char* srcA = ws + WS_COMB + (size_t)blockIdx.x * 8192;
    char* dstA = (char*)sA;
    async_g2l_16(srcA + tid * 16, dstA + tid * 16);
    async_g2l_16(srcA + 4096 + tid * 16, dstA + 4096 + tid * 16);
  }
  __syncthreads();

  const int hl = lane & 15, rq = lane >> 4;
  const int h0 = wv * 32 + hl, h1 = h0 + 16;
  f32x4 acc0 = {0.f, 0.f, 0.f, 0.f};
  f32x4 acc1 = {0.f, 0.f, 0.f, 0.f};
#pragma unroll
  for (int kk = 0; kk < 8; ++kk) {
    const short8 av = *(const short8*)&sA[swzW(hl, kk * 32 + rq * 8)];
    const short8 b0 = *(const short8*)&sW[swzW(h0, kk * 32 + rq * 8)];
    const short8 b1 = *(const short8*)&sW[swzW(h1, kk * 32 + rq * 8)];
    acc0 = __builtin_amdgcn_mfma_f32_16x16x32_bf16(av, b0, acc0, 0, 0, 0);
    acc1 = __builtin_amdgcn_mfma_f32_16x16x32_bf16(av, b1, acc1, 0, 0, 0);
  }
  const float fb10 = fb1[h0], fb11 = fb1[h1];
  const float fw20 = fw2[h0], fw21 = fw2[h1];
#pragma unroll
  for (int r = 0; r < 4; ++r) {
    float v = fmaxf(acc0[r] + fb10, 0.f) * fw20
            + fmaxf(acc1[r] + fb11, 0.f) * fw21;
    v += __shfl_xor(v, 1, 64);
    v += __shfl_xor(v, 2, 64);
    v += __shfl_xor(v, 4, 64);
    v += __shfl_xor(v, 8, 64);
    if (hl == 0) sO[wv * 16 + rq * 4 + r] = v;
  }
  __syncthreads();
  if (tid < 16)
    out[bb + tid] = sO[tid] + sO[16 + tid] + sO[32 + tid] + sO[48 + tid] + fb2[0];
}

extern "C" void kernel_launch(void* const* d_in, const int* in_sizes, int n_in,
                              void* d_out, int out_size, void* d_ws, size_t ws_size,
                              hipStream_t stream) {
  const int*   uf   = (const int*)d_in[0];
  const int*   tif  = (const int*)d_in[1];
  const int*   bseq = (const int*)d_in[2];
  const float* e0   = (const float*)d_in[3];
  const float* e1   = (const float*)d_in[4];
  const float* ei   = (const float*)d_in[5];
  const float* aw1  = (const float*)d_in[6];
  const float* ab1  = (const float*)d_in[7];
  const float* aw2  = (const float*)d_in[8];
  // d_in[9] = ab2 (unused: softmax shift-invariant)
  const float* fw1  = (const float*)d_in[10];
  const float* fb1  = (const float*)d_in[11];
  const float* fw2  = (const float*)d_in[12];
  const float* fb2  = (const float*)d_in[13];
  float* o = (float*)d_out;
  char* ws = (char*)d_ws;

  din_prep<<<dim3(192), dim3(256), 0, stream>>>(aw1, fw1, ws);
  din_prep2<<<dim3(4096), dim3(128), 0, stream>>>(uf, tif, e0, e1, ei, ab1, ws);
  din_main<<<dim3(4096), dim3(256), 0, stream>>>(bseq, ei, aw2, ws);
  din_fc<<<dim3(256), dim3(256), 0, stream>>>(fb1, fw2, fb2, ws, o);
}

// Round 10
// 62.582 us; speedup vs baseline: 2.7384x; 1.0144x over previous
//
#include <hip/hip_runtime.h>
#include <math.h>

// DIN fused, round 10: prep2 folded into din_main — cH computed per-block via
// MFMA (A=Bm frag-major, B=packed t fragments), bias ab1 added into acc-init.
//  k0 prep: A'/D'/Bm frag-major bf16; fw1T pre-swizzled bf16.
//  k1 main: one b per block (4096 blocks): gather -> swizzled bf16 LDS ->
//           MFMA (swapped operands) -> softmax -> pool -> comb.
//  k2 fc  : relu(comb@fw1+b1)@fw2+b2 via MFMA, 16 b/block.

#define S_LEN 200
#define S_PAD 208

typedef __attribute__((ext_vector_type(8))) short short8;
typedef __attribute__((ext_vector_type(4))) float f32x4;

__device__ __forceinline__ unsigned short f2b(float f) {
  union { float f; unsigned u; } x; x.f = f;
  unsigned r = x.u + 0x7fffu + ((x.u >> 16) & 1u);
  return (unsigned short)(r >> 16);
}
__device__ __forceinline__ float b2f(unsigned short h) {
  union { unsigned u; float f; } x; x.u = ((unsigned)h) << 16; return x.f;
}
__device__ __forceinline__ unsigned cvt_pk_bf16(float lo, float hi) {
  unsigned r;
  asm("v_cvt_pk_bf16_f32 %0, %1, %2" : "=v"(r) : "v"(lo), "v"(hi));
  return r;
}

// [row][64] bf16 tile, row stride 128 B (XOR row&7 into byte b4..6)
__device__ __forceinline__ int swzB(int row, int col) {
  int byte = row * 128 + col * 2;
  byte ^= (row & 7) << 4;
  return byte >> 1;
}
// [row][256] bf16 tile, row stride 512 B
__device__ __forceinline__ int swzW(int row, int col) {
  int byte = row * 512 + col * 2;
  byte ^= (row & 7) << 4;
  return byte >> 1;
}

__device__ __forceinline__ void async_g2l_16(const void* g, void* l) {
  __builtin_amdgcn_global_load_lds(
      (const __attribute__((address_space(1))) void*)g,
      (__attribute__((address_space(3))) void*)l, 16, 0, 0);
}

// DPP 16-lane reduce (xor1, xor2, ror4, ror8)
template <int CTRL>
__device__ __forceinline__ float dpp_add(float v) {
  const int t = __builtin_amdgcn_mov_dpp(__float_as_int(v), CTRL, 0xF, 0xF, true);
  return v + __int_as_float(t);
}
__device__ __forceinline__ float rowReduce16(float v) {
  v = dpp_add<0xB1>(v);
  v = dpp_add<0x4E>(v);
  v = dpp_add<0x124>(v);
  v = dpp_add<0x128>(v);
  return v;
}
__device__ __forceinline__ float permAdd16(float p) {
  float a = p, b = p;
  asm("v_permlane16_swap_b32 %0, %1" : "+v"(a), "+v"(b));
  return a + b;
}
__device__ __forceinline__ float permAdd32(float p) {
  float a = p, b = p;
  asm("v_permlane32_swap_b32 %0, %1" : "+v"(a), "+v"(b));
  return a + b;
}
__device__ __forceinline__ float waveSum64(float v) {
  return permAdd32(permAdd16(rowReduce16(v)));
}

// ---------------- workspace layout (bytes) ----------------
#define WS_COMB 0          // bf16-swz [256 tiles][16][256]  (2 MB)
#define WS_AT   2097152    // A' = W1a+W1c frag-major bf16, 16 KB
#define WS_DT   2113536    // D' = W1d     frag-major bf16, 16 KB
#define WS_BM   2129920    // Bm = W1b-W1c frag-major bf16, 16 KB
#define WS_FW1T 2146304    // fw1^T pre-swizzled bf16, 64 KB

// ================= k0: prep =================
__global__ __launch_bounds__(256)
void din_prep(const float* __restrict__ aw1, const float* __restrict__ fw1,
              char* __restrict__ ws)
{
  unsigned short* ATc  = (unsigned short*)(ws + WS_AT);
  unsigned short* DTc  = (unsigned short*)(ws + WS_DT);
  unsigned short* BMc  = (unsigned short*)(ws + WS_BM);
  unsigned short* FW1T = (unsigned short*)(ws + WS_FW1T);
  const int blk = blockIdx.x, tid = threadIdx.x;

  if (blk < 64) {               // A', D', Bm in fragment-major layout
    const int i = (blk & 31) * 256 + tid;   // 0..8191
    const int h = i >> 6, d = i & 63;
    // frag index: lane reads 16B at ((hg*2+ht)*2+kk)*512 + lane*8
    const int hg = h >> 5, ht = (h >> 4) & 1, hl = h & 15;
    const int kk = d >> 5, rq = (d >> 3) & 3, j = d & 7;
    const int o = (hg * 2 + ht) * 1024 + kk * 512 + rq * 128 + hl * 8 + j;
    if (blk < 32) {
      const float a  = aw1[d * 128 + h];
      const float c  = aw1[(128 + d) * 128 + h];
      const float dd = aw1[(192 + d) * 128 + h];
      ATc[o] = f2b(a + c);
      DTc[o] = f2b(dd);
    } else {
      BMc[o] = f2b(aw1[(64 + d) * 128 + h] - aw1[(128 + d) * 128 + h]);
    }
  } else {                      // fw1T swizzled image
    const int i = (blk - 64) * 256 + tid;
    const int o = 2 * i;
    const int h = o >> 9;
    const int rr = o & 511;
    const int d = (rr ^ ((h & 7) << 4)) >> 1;
    FW1T[i] = f2b(fw1[d * 128 + h]);
  }
}

// ================= k1: main (one b per block) =================
__global__ __launch_bounds__(256, 4)
void din_main(const int* __restrict__ uf, const int* __restrict__ tif,
              const int* __restrict__ bseq,
              const float* __restrict__ e0, const float* __restrict__ e1,
              const float* __restrict__ ei,
              const float* __restrict__ ab1, const float* __restrict__ aw2,
              char* __restrict__ ws)
{
  __shared__ unsigned short sBeh[13312];  // 26624 B, swizzled bf16 [208][64]
  __shared__ float sPart[4][S_PAD];       // 3328
  __shared__ float sScores[S_PAD];        // 832
  __shared__ float sPool[4][64];          // 1024
  __shared__ float sRedS[4];

  unsigned short* combS = (unsigned short*)(ws + WS_COMB);
  const unsigned short* ATc = (const unsigned short*)(ws + WS_AT);
  const unsigned short* DTc = (const unsigned short*)(ws + WS_DT);
  const unsigned short* BMc = (const unsigned short*)(ws + WS_BM);

  const int b    = blockIdx.x;
  const int tid  = threadIdx.x;
  const int lane = tid & 63;
  const int wv   = tid >> 6;       // 0..3 = h-group (32 cols each)
  const int hl   = lane & 15;
  const int rq   = lane >> 4;      // 0..3

  const int ti = tif[b];

  // ---- 1. issue all 13 gathers + t-row fragments immediately ----
  float4 gv[13];
#pragma unroll
  for (int it = 0; it < 13; ++it) {
    const int row = it * 16 + (tid >> 4);
    if (row < S_LEN) {
      const int idx = bseq[b * S_LEN + row];
      gv[it] = *(const float4*)(ei + (size_t)idx * 64 + (tid & 15) * 4);
    }
  }
  const float* trow = ei + (size_t)ti * 64;
  const float4 tx0 = *(const float4*)(trow + rq * 8);
  const float4 tx1 = *(const float4*)(trow + rq * 8 + 4);
  const float4 ty0 = *(const float4*)(trow + 32 + rq * 8);
  const float4 ty1 = *(const float4*)(trow + 32 + rq * 8 + 4);
  __builtin_amdgcn_sched_barrier(0);

  // ---- 2. pad rows 200..207 ----
  if (tid < 128) {
    const int row = 200 + (tid >> 4), c = (tid & 15) * 4;
    ushort4 z = {0, 0, 0, 0};
    *(ushort4*)&sBeh[swzB(row, c)] = z;
  }

  // ---- 3. comb user/target parts (threads 0..191) ----
  {
    unsigned short* ct = combS + (size_t)(b >> 4) * 4096;
    const int row = b & 15;
    if (tid < 64) {
      const int u0 = uf[2 * b];
      ct[swzW(row, tid)] = f2b(e0[(size_t)u0 * 64 + tid]);
    } else if (tid < 128) {
      const int u1 = uf[2 * b + 1];
      ct[swzW(row, 64 + (tid - 64))] = f2b(e1[(size_t)u1 * 64 + (tid - 64)]);
    } else if (tid < 192) {
      ct[swzW(row, 192 + (tid - 128))] = f2b(trow[tid - 128]);
    }
  }

  // ---- 4. per-lane constants ----
  const float4 w2v0 = *(const float4*)(aw2 + wv * 32 + rq * 4);
  const float4 w2v1 = *(const float4*)(aw2 + wv * 32 + 16 + rq * 4);
  const f32x4 abv0 = *(const f32x4*)(ab1 + wv * 32 + rq * 4);
  const f32x4 abv1 = *(const f32x4*)(ab1 + wv * 32 + 16 + rq * 4);

  // ---- 5. W_eff fragments: w[ht][kk] = A' + t(.)D' ; pack ttB ----
  const float tt0[8] = {tx0.x, tx0.y, tx0.z, tx0.w, tx1.x, tx1.y, tx1.z, tx1.w};
  const float tt1[8] = {ty0.x, ty0.y, ty0.z, ty0.w, ty1.x, ty1.y, ty1.z, ty1.w};
  short8 w[2][2];
#pragma unroll
  for (int ht = 0; ht < 2; ++ht) {
#pragma unroll
    for (int kk = 0; kk < 2; ++kk) {
      const int fo = (wv * 2 + ht) * 1024 + kk * 512 + lane * 8;
      const short8 a8 = *(const short8*)(ATc + fo);
      const short8 d8 = *(const short8*)(DTc + fo);
      const float* tk = kk ? tt1 : tt0;
      union { short8 s; unsigned u[4]; } o;
#pragma unroll
      for (int p = 0; p < 4; ++p) {
        const float lo = fmaf(tk[2*p],   b2f((unsigned short)d8[2*p]),   b2f((unsigned short)a8[2*p]));
        const float hi = fmaf(tk[2*p+1], b2f((unsigned short)d8[2*p+1]), b2f((unsigned short)a8[2*p+1]));
        o.u[p] = cvt_pk_bf16(lo, hi);
      }
      w[ht][kk] = o.s;
    }
  }
  short8 ttB0, ttB1;
  {
    union { short8 s; unsigned u[4]; } o;
#pragma unroll
    for (int p = 0; p < 4; ++p) o.u[p] = cvt_pk_bf16(tt0[2*p], tt0[2*p+1]);
    ttB0 = o.s;
#pragma unroll
    for (int p = 0; p < 4; ++p) o.u[p] = cvt_pk_bf16(tt1[2*p], tt1[2*p+1]);
    ttB1 = o.s;
  }

  // ---- 6. commit gathers -> swizzled bf16 LDS (gv dies here) ----
#pragma unroll
  for (int it = 0; it < 13; ++it) {
    const int row = it * 16 + (tid >> 4);
    if (row < S_LEN) {
      const float4 v = gv[it];
      uint2 pk;
      pk.x = cvt_pk_bf16(v.x, v.y);
      pk.y = cvt_pk_bf16(v.z, v.w);
      *(uint2*)&sBeh[swzB(row, (tid & 15) * 4)] = pk;
    }
  }

  // ---- 7. cH via MFMA: accInit[h][*] = t.Bm[:,h] + ab1[h] ----
  f32x4 accInit0, accInit1;
  {
    const f32x4 z = {0.f, 0.f, 0.f, 0.f};
    f32x4 c0 = z, c1 = z;
    const short8 bm00 = *(const short8*)(BMc + (wv * 2) * 1024 + lane * 8);
    const short8 bm01 = *(const short8*)(BMc + (wv * 2) * 1024 + 512 + lane * 8);
    const short8 bm10 = *(const short8*)(BMc + (wv * 2 + 1) * 1024 + lane * 8);
    const short8 bm11 = *(const short8*)(BMc + (wv * 2 + 1) * 1024 + 512 + lane * 8);
    c0 = __builtin_amdgcn_mfma_f32_16x16x32_bf16(bm00, ttB0, c0, 0, 0, 0);
    c0 = __builtin_amdgcn_mfma_f32_16x16x32_bf16(bm01, ttB1, c0, 0, 0, 0);
    c1 = __builtin_amdgcn_mfma_f32_16x16x32_bf16(bm10, ttB0, c1, 0, 0, 0);
    c1 = __builtin_amdgcn_mfma_f32_16x16x32_bf16(bm11, ttB1, c1, 0, 0, 0);
#pragma unroll
    for (int r = 0; r < 4; ++r) {
      accInit0[r] = c0[r] + abv0[r];
      accInit1[r] = c1[r] + abv1[r];
    }
  }
  __syncthreads();  // (1) beh ready

  // ---- 8. MFMA (swapped operands): C[h][s], wave owns 32 h-cols ----
#pragma unroll 2
  for (int tile = 0; tile < 13; ++tile) {
    const short8 av0 = *(const short8*)&sBeh[swzB(tile * 16 + hl, rq * 8)];
    const short8 av1 = *(const short8*)&sBeh[swzB(tile * 16 + hl, 32 + rq * 8)];
    f32x4 acc = accInit0;
    acc = __builtin_amdgcn_mfma_f32_16x16x32_bf16(w[0][0], av0, acc, 0, 0, 0);
    acc = __builtin_amdgcn_mfma_f32_16x16x32_bf16(w[0][1], av1, acc, 0, 0, 0);
    float p;
    p = fmaxf(acc[0], 0.f) * w2v0.x;
    p = fmaf(fmaxf(acc[1], 0.f), w2v0.y, p);
    p = fmaf(fmaxf(acc[2], 0.f), w2v0.z, p);
    p = fmaf(fmaxf(acc[3], 0.f), w2v0.w, p);
    f32x4 acc2 = accInit1;
    acc2 = __builtin_amdgcn_mfma_f32_16x16x32_bf16(w[1][0], av0, acc2, 0, 0, 0);
    acc2 = __builtin_amdgcn_mfma_f32_16x16x32_bf16(w[1][1], av1, acc2, 0, 0, 0);
    p = fmaf(fmaxf(acc2[0], 0.f), w2v1.x, p);
    p = fmaf(fmaxf(acc2[1], 0.f), w2v1.y, p);
    p = fmaf(fmaxf(acc2[2], 0.f), w2v1.z, p);
    p = fmaf(fmaxf(acc2[3], 0.f), w2v1.w, p);
    p = permAdd32(permAdd16(p));   // reduce over q-groups (pure VALU)
    if (lane < 16) sPart[wv][tile * 16 + lane] = p;
  }
  __syncthreads();  // (2) partials ready

  // ---- 9. softmax (no max-shift; shift-invariant, |s| small) ----
  float e = 0.f;
  if (tid < S_PAD) {
    if (tid < S_LEN)
      e = __expf((sPart[0][tid] + sPart[1][tid]) + (sPart[2][tid] + sPart[3][tid]));
    sScores[tid] = e;
  }
  {
    const float s = waveSum64(e);
    if (lane == 0) sRedS[wv] = s;
  }
  __syncthreads();  // (3) sScores + sums ready

  const float invS = 1.f / (sRedS[0] + sRedS[1] + sRedS[2] + sRedS[3]);

  // ---- 10. pooling ----
  {
    const int e2 = lane & 31, rr = lane >> 5;
    float p0 = 0.f, p1 = 0.f;
#pragma unroll
    for (int k = 0; k < 13; ++k) {
      const int base = 16 * k + 4 * wv + 2 * rr;
      const float2 sc2 = *(const float2*)&sScores[base];
      const unsigned u0 = *(const unsigned*)&sBeh[swzB(base, e2 * 2)];
      p0 = fmaf(sc2.x, __int_as_float((int)(u0 << 16)), p0);
      p1 = fmaf(sc2.x, __int_as_float((int)(u0 & 0xffff0000u)), p1);
      const unsigned u1 = *(const unsigned*)&sBeh[swzB(base + 1, e2 * 2)];
      p0 = fmaf(sc2.y, __int_as_float((int)(u1 << 16)), p0);
      p1 = fmaf(sc2.y, __int_as_float((int)(u1 & 0xffff0000u)), p1);
    }
    p0 = permAdd32(p0);
    p1 = permAdd32(p1);
    if (lane < 32) {
      float2 pr; pr.x = p0; pr.y = p1;
      *(float2*)&sPool[wv][e2 * 2] = pr;
    }
  }
  __syncthreads();  // (4) sPool ready

  if (tid < 64) {
    const float a = sPool[0][tid] + sPool[1][tid] + sPool[2][tid] + sPool[3][tid];
    combS[(size_t)(b >> 4) * 4096 + swzW(b & 15, 128 + tid)] = f2b(a * invS);
  }
}

// ================= k2: FC head =================
__global__ __launch_bounds__(256, 2)
void din_fc(const float* __restrict__ fb1, const float* __restrict__ fw2,
            const float* __restrict__ fb2, const char* __restrict__ ws,
            float* __restrict__ out)
{
  __shared__ unsigned short sW[32768];   // fw1T swizzled image, 64 KB
  __shared__ unsigned short sA[4096];    // comb tile (pre-swizzled bf16), 8 KB
  __shared__ float sO[64];

  const int tid  = threadIdx.x;
  const int lane = tid & 63;
  const int wv   = tid >> 6;
  const int bb   = blockIdx.x * 16;

  {
    const char* srcW = ws + WS_FW1T;
    char* dstW = (char*)sW;
#pragma unroll
    for (int it = 0; it < 16; ++it)
      async_g2l_16(srcW + it * 4096 + tid * 16, dstW + it * 4096 + tid * 16);
    const char* srcA = ws + WS_COMB + (size_t)blockIdx.x * 8192;
    char* dstA = (char*)sA;
    async_g2l_16(srcA + tid * 16, dstA + tid * 16);
    async_g2l_16(srcA + 4096 + tid * 16, dstA + 4096 + tid * 16);
  }
  __syncthreads();

  const int hl = lane & 15, rq = lane >> 4;
  const int h0 = wv * 32 + hl, h1 = h0 + 16;
  f32x4 acc0 = {0.f, 0.f, 0.f, 0.f};
  f32x4 acc1 = {0.f, 0.f, 0.f, 0.f};
#pragma unroll
  for (int kk = 0; kk < 8; ++kk) {
    const short8 av = *(const short8*)&sA[swzW(hl, kk * 32 + rq * 8)];
    const short8 b0 = *(const short8*)&sW[swzW(h0, kk * 32 + rq * 8)];
    const short8 b1 = *(const short8*)&sW[swzW(h1, kk * 32 + rq * 8)];
    acc0 = __builtin_amdgcn_mfma_f32_16x16x32_bf16(av, b0, acc0, 0, 0, 0);
    acc1 = __builtin_amdgcn_mfma_f32_16x16x32_bf16(av, b1, acc1, 0, 0, 0);
  }
  const float fb10 = fb1[h0], fb11 = fb1[h1];
  const float fw20 = fw2[h0], fw21 = fw2[h1];
#pragma unroll
  for (int r = 0; r < 4; ++r) {
    float v = fmaxf(acc0[r] + fb10, 0.f) * fw20
            + fmaxf(acc1[r] + fb11, 0.f) * fw21;
    v += __shfl_xor(v, 1, 64);
    v += __shfl_xor(v, 2, 64);
    v += __shfl_xor(v, 4, 64);
    v += __shfl_xor(v, 8, 64);
    if (hl == 0) sO[wv * 16 + rq * 4 + r] = v;
  }
  __syncthreads();
  if (tid < 16)
    out[bb + tid] = sO[tid] + sO[16 + tid] + sO[32 + tid] + sO[48 + tid] + fb2[0];
}

extern "C" void kernel_launch(void* const* d_in, const int* in_sizes, int n_in,
                              void* d_out, int out_size, void* d_ws, size_t ws_size,
                              hipStream_t stream) {
  const int*   uf   = (const int*)d_in[0];
  const int*   tif  = (const int*)d_in[1];
  const int*   bseq = (const int*)d_in[2];
  const float* e0   = (const float*)d_in[3];
  const float* e1   = (const float*)d_in[4];
  const float* ei   = (const float*)d_in[5];
  const float* aw1  = (const float*)d_in[6];
  const float* ab1  = (const float*)d_in[7];
  const float* aw2  = (const float*)d_in[8];
  // d_in[9] = ab2 (unused: softmax shift-invariant)
  const float* fw1  = (const float*)d_in[10];
  const float* fb1  = (const float*)d_in[11];
  const float* fw2  = (const float*)d_in[12];
  const float* fb2  = (const float*)d_in[13];
  float* o = (float*)d_out;
  char* ws = (char*)d_ws;

  din_prep<<<dim3(192), dim3(256), 0, stream>>>(aw1, fw1, ws);
  din_main<<<dim3(4096), dim3(256), 0, stream>>>(uf, tif, bseq, e0, e1, ei,
                                                 ab1, aw2, ws);
  din_fc<<<dim3(256), dim3(256), 0, stream>>>(fb1, fw2, fb2, ws, o);
}